// Round 1
// baseline (526.580 us; speedup 1.0000x reference)
//
#include <hip/hip_runtime.h>

// Fused gated aggregator:
//   gates = sigmoid(nodes @ Wg + bg); data = nodes @ Wt + bt
//   out[B,D] = owner_masks(float) @ (data * gates)
// v2: masks global->frag regs (no LDS), double-buffered nodes/vt LDS,
//     ONE barrier per 32-node chunk, cvt_pk bf16 packing, rcp-based sigmoid.

#define NTOT   500000
#define NBLK   512
#define NCHUNK 15625   // NTOT / 32, exact

typedef __attribute__((ext_vector_type(8))) unsigned short ushort8;
typedef __bf16 bf16x8 __attribute__((ext_vector_type(8)));
typedef __bf16 bf16x2 __attribute__((ext_vector_type(2)));
typedef __attribute__((ext_vector_type(4))) float f32x4;

// packed f32x2 -> bf16x2 (RNE; lowers to v_cvt_pk_bf16_f32)
static __device__ __forceinline__ unsigned int pkbf(float a, float b) {
  bf16x2 v;
  v[0] = (__bf16)a;
  v[1] = (__bf16)b;
  return __builtin_bit_cast(unsigned int, v);
}

// int 0/1 pair -> packed bf16 {lo,hi}; bf16(1.0) = 0x3F80. 2 cndmask + 1 or.
static __device__ __forceinline__ unsigned int mkw(int lo, int hi) {
  return (lo ? 0x3F80u : 0u) | (hi ? 0x3F800000u : 0u);
}

template <bool ATOMIC>
__global__ __launch_bounds__(256, 2)
void agg_main(const float* __restrict__ nodes, const int* __restrict__ masks,
              const float* __restrict__ Wt, const float* __restrict__ bt,
              const float* __restrict__ Wg, const float* __restrict__ bg,
              float* __restrict__ outp) {
  // double-buffered; strides padded for <=2-way bank aliasing on b128 reads
  __shared__ __align__(16) unsigned short nodes_s[2][32][136];  // [buf][node][s]
  __shared__ __align__(16) unsigned short vt_s[2][128][40];     // [buf][d][node]

  const int tid = threadIdx.x;
  const int lane = tid & 63;
  const int w = tid >> 6;    // wave 0..3
  const int q = lane >> 4;   // quad 0..3
  const int r = lane & 15;

  // ---- preload W as B-operand fragments (VGPR-resident), + biases ----
  // B-frag mapping for 16x16x32: n = lane&15, k = quad*8 + j
  bf16x8 Wf[2][4][2];  // [data/gate][ks][nt]
  float btr[2], bgr[2];
#pragma unroll
  for (int nt = 0; nt < 2; ++nt) {
    const int d = w * 32 + nt * 16 + r;
    btr[nt] = bt[d];
    bgr[nt] = bg[d];
#pragma unroll
    for (int ks = 0; ks < 4; ++ks) {
      ushort8 ft, fg;
#pragma unroll
      for (int j = 0; j < 8; ++j) {
        const int k = ks * 32 + q * 8 + j;  // s index
        ft[j] = __builtin_bit_cast(unsigned short, (__bf16)Wt[k * 128 + d]);
        fg[j] = __builtin_bit_cast(unsigned short, (__bf16)Wg[k * 128 + d]);
      }
      Wf[0][ks][nt] = __builtin_bit_cast(bf16x8, ft);
      Wf[1][ks][nt] = __builtin_bit_cast(bf16x8, fg);
    }
  }

  // pooling accumulators: wave w owns out rows w*32..w*32+31, ALL 128 cols
  f32x4 acc[2][8];
  const f32x4 fzero = {0.f, 0.f, 0.f, 0.f};
#pragma unroll
  for (int i = 0; i < 2; ++i)
#pragma unroll
    for (int j = 0; j < 8; ++j) acc[i][j] = fzero;

  const int bid = blockIdx.x;
  const int c0 = (int)(((long long)bid * NCHUNK) / NBLK);
  const int c1 = (int)(((long long)(bid + 1) * NCHUNK) / NBLK);
  const int n = c1 - c0;

  // per-thread mask row pointers (wave w, sub-row mt*16+r, node offset q*8)
  const int* mrow0 = masks + (size_t)(w * 32 + r) * NTOT + q * 8;
  const int* mrow1 = mrow0 + (size_t)16 * NTOT;

  float4 nf[4];            // node prefetch (1 chunk deep)
  int4 miA[2][2], miB[2][2];  // mask prefetch, two named sets (static indexing)

  auto issue_nodes = [&](int c) {
    const float4* p = (const float4*)(nodes + (size_t)c * 32 * 128);
#pragma unroll
    for (int it = 0; it < 4; ++it) nf[it] = p[it * 256 + tid];
  };

  auto issue_masks = [&](int4 (&mi)[2][2], int c) {
    const int k0 = c * 32;
    mi[0][0] = *(const int4*)(mrow0 + k0);
    mi[0][1] = *(const int4*)(mrow0 + k0 + 4);
    mi[1][0] = *(const int4*)(mrow1 + k0);
    mi[1][1] = *(const int4*)(mrow1 + k0 + 4);
  };

  auto stage = [&](int buf) {
#pragma unroll
    for (int it = 0; it < 4; ++it) {
      const int flat = it * 256 + tid;
      const int nrow = flat >> 5, nc4 = flat & 31;  // 32 rows x 32 float4
      uint2 u;
      u.x = pkbf(nf[it].x, nf[it].y);
      u.y = pkbf(nf[it].z, nf[it].w);
      *(uint2*)&nodes_s[buf][nrow][nc4 * 4] = u;
    }
  };

  // pooling: out[b][d] += mask[b][node] * V[node][d], K=32 (16 MFMA)
  auto pool = [&](const int4 (&mi)[2][2], int buf) {
    uint4 u0, u1;
    u0.x = mkw(mi[0][0].x, mi[0][0].y);
    u0.y = mkw(mi[0][0].z, mi[0][0].w);
    u0.z = mkw(mi[0][1].x, mi[0][1].y);
    u0.w = mkw(mi[0][1].z, mi[0][1].w);
    u1.x = mkw(mi[1][0].x, mi[1][0].y);
    u1.y = mkw(mi[1][0].z, mi[1][0].w);
    u1.z = mkw(mi[1][1].x, mi[1][1].y);
    u1.w = mkw(mi[1][1].z, mi[1][1].w);
    const bf16x8 af0 = __builtin_bit_cast(bf16x8, u0);
    const bf16x8 af1 = __builtin_bit_cast(bf16x8, u1);
#pragma unroll
    for (int nt = 0; nt < 8; ++nt) {
      const bf16x8 bfr = *(const bf16x8*)&vt_s[buf][nt * 16 + r][q * 8];
      acc[0][nt] = __builtin_amdgcn_mfma_f32_16x16x32_bf16(af0, bfr, acc[0][nt], 0, 0, 0);
      acc[1][nt] = __builtin_amdgcn_mfma_f32_16x16x32_bf16(af1, bfr, acc[1][nt], 0, 0, 0);
    }
  };

  // GEMM1 [32 x 128s] @ W[128s x 64d-slice] + gated epilogue -> vt_s[buf]
  auto gemm_epi = [&](int buf) {
    f32x4 aD[2][2], aG[2][2];
#pragma unroll
    for (int i2 = 0; i2 < 2; ++i2)
#pragma unroll
      for (int j2 = 0; j2 < 2; ++j2) { aD[i2][j2] = fzero; aG[i2][j2] = fzero; }
#pragma unroll
    for (int ks = 0; ks < 4; ++ks) {
      // A-frag: m = lane&15 (+16*mt), k = ks*32 + quad*8 + j
      const bf16x8 a0 = *(const bf16x8*)&nodes_s[buf][r][ks * 32 + q * 8];
      const bf16x8 a1 = *(const bf16x8*)&nodes_s[buf][16 + r][ks * 32 + q * 8];
#pragma unroll
      for (int nt = 0; nt < 2; ++nt) {
        aD[0][nt] = __builtin_amdgcn_mfma_f32_16x16x32_bf16(a0, Wf[0][ks][nt], aD[0][nt], 0, 0, 0);
        aD[1][nt] = __builtin_amdgcn_mfma_f32_16x16x32_bf16(a1, Wf[0][ks][nt], aD[1][nt], 0, 0, 0);
        aG[0][nt] = __builtin_amdgcn_mfma_f32_16x16x32_bf16(a0, Wf[1][ks][nt], aG[0][nt], 0, 0, 0);
        aG[1][nt] = __builtin_amdgcn_mfma_f32_16x16x32_bf16(a1, Wf[1][ks][nt], aG[1][nt], 0, 0, 0);
      }
    }
    // epilogue: V = (data+bt)*sigmoid(gate+bg); write V^T[d][node]
    // C/D layout: col = lane&15, row = quad*4 + reg
#pragma unroll
    for (int mt = 0; mt < 2; ++mt)
#pragma unroll
      for (int nt = 0; nt < 2; ++nt) {
        const int d = w * 32 + nt * 16 + r;
        float v[4];
#pragma unroll
        for (int reg = 0; reg < 4; ++reg) {
          const float x = aD[mt][nt][reg] + btr[nt];
          const float g = aG[mt][nt][reg] + bgr[nt];
          v[reg] = x * __builtin_amdgcn_rcpf(1.f + __expf(-g));
        }
        uint2 u;
        u.x = pkbf(v[0], v[1]);
        u.y = pkbf(v[2], v[3]);
        *(uint2*)&vt_s[buf][d][mt * 16 + q * 4] = u;
      }
  };

  int i = 0;
  // one barrier per chunk; all cross-wave hazards separated by >=1 barrier via
  // buffer parity (nodes_s/vt_s double-buffered, mask sets alternate A/B)
  auto body = [&](int buf, int4 (&mip)[2][2], int4 (&mii)[2][2]) {
    stage(buf);               // nf -> nodes_s[buf] (consumes nf)
    __syncthreads();          // drains stage writes; prefetches issued AFTER
    const int c = c0 + i;
    if (i + 1 < n) issue_nodes(c + 1);       // in flight across pool+gemm+epi
    if (i > 0) pool(mip, buf ^ 1);           // chunk c-1 (vt in other buffer)
    if (i + 1 < n) issue_masks(mii, c + 1);  // in flight across gemm+epi
    gemm_epi(buf);
    ++i;
  };

  if (n > 0) {
    issue_nodes(c0);
    issue_masks(miA, c0);  // even chunk-index -> set A
  }
  while (i < n) {
    body(0, miB, miB);              // even i: pool odd chunk (B), issue odd (B)
    if (i < n) body(1, miA, miA);   // odd  i: pool even chunk (A), issue even (A)
  }
  __syncthreads();
  if (n > 0) {
    if ((n - 1) & 1) pool(miB, 1);
    else             pool(miA, 0);
  }

  // ---- write per-block partial (or atomic accumulate) ----
#pragma unroll
  for (int mt = 0; mt < 2; ++mt)
#pragma unroll
    for (int nt = 0; nt < 8; ++nt)
#pragma unroll
      for (int reg = 0; reg < 4; ++reg) {
        const int b = w * 32 + mt * 16 + q * 4 + reg;
        const int d = nt * 16 + r;
        if (ATOMIC)
          atomicAdd(&outp[b * 128 + d], acc[mt][nt][reg]);
        else
          outp[(size_t)bid * 16384 + b * 128 + d] = acc[mt][nt][reg];
      }
}

__global__ __launch_bounds__(256)
void agg_reduce(const float* __restrict__ part, float* __restrict__ out) {
  // 512 blocks x 256 thr = 131072 = 8 groups x 16384 outputs; 64 partials each
  const int gid = blockIdx.x * 256 + threadIdx.x;
  const int i = gid & 16383;
  const int grp = gid >> 14;
  const float* p = part + (size_t)grp * 64 * 16384 + i;
  float s = 0.f;
#pragma unroll 8
  for (int g = 0; g < 64; ++g) s += p[(size_t)g * 16384];
  atomicAdd(&out[i], s);
}

extern "C" void kernel_launch(void* const* d_in, const int* in_sizes, int n_in,
                              void* d_out, int out_size, void* d_ws, size_t ws_size,
                              hipStream_t stream) {
  const float* nodes = (const float*)d_in[0];
  const int*   masks = (const int*)d_in[1];
  const float* Wt    = (const float*)d_in[2];
  const float* bt    = (const float*)d_in[3];
  const float* Wg    = (const float*)d_in[4];
  const float* bg    = (const float*)d_in[5];
  float* out = (float*)d_out;

  hipMemsetAsync(d_out, 0, (size_t)out_size * sizeof(float), stream);

  const size_t need = (size_t)NBLK * 16384 * sizeof(float);
  if (ws_size >= need) {
    agg_main<false><<<NBLK, 256, 0, stream>>>(nodes, masks, Wt, bt, Wg, bg, (float*)d_ws);
    agg_reduce<<<512, 256, 0, stream>>>((const float*)d_ws, out);
  } else {
    agg_main<true><<<NBLK, 256, 0, stream>>>(nodes, masks, Wt, bt, Wg, bg, out);
  }
}